// Round 13
// baseline (368.227 us; speedup 1.0000x reference)
//
#include <hip/hip_runtime.h>
#include <hip/hip_bf16.h>

#define SEQ 16384
#define DIM 1280
#define NHEAD 16
#define HD 80
#define NWIN 256   // SEQ / 64
#define QKV_N 3840 // 3 * DIM
#define GK 1280    // K of both GEMMs
#define NT 20      // GK / 64

typedef __attribute__((ext_vector_type(8))) short bf16x8;
typedef __attribute__((ext_vector_type(8))) unsigned short ushort8;
typedef __attribute__((ext_vector_type(4))) float f32x4;

__device__ inline unsigned short f2bf(float x) {
    union { __hip_bfloat16 b; unsigned short u; } cv;
    cv.b = __float2bfloat16(x);
    return cv.u;
}
__device__ inline float bf2f(unsigned short u) {
    union { unsigned int i; float f; } cv;
    cv.i = ((unsigned int)u) << 16;
    return cv.f;
}

// async global->LDS, 16B per lane, wave-uniform LDS base + lane*16
#define GLD16(g, l) __builtin_amdgcn_global_load_lds( \
    (const __attribute__((address_space(1))) void*)(g), \
    (__attribute__((address_space(3))) void*)(l), 16, 0, 0)

#define SBAR() asm volatile("s_barrier" ::: "memory")

// ---------------------------------------------------------------------------
// f32 -> bf16 convert, weights only (hidden conversion is fused into the
// QKV GEMM's A-staging). One dispatch, segmented grid.
// ---------------------------------------------------------------------------
#define CVT_W0 2400    // QKV_N*DIM / 2048
#define CVT_W1 3200    // + DIM*DIM / 2048
__global__ __launch_bounds__(256) void cvt_weights(
    const float* __restrict__ s0, unsigned short* __restrict__ d0,
    const float* __restrict__ s1, unsigned short* __restrict__ d1)
{
    const int b = blockIdx.x;
    const float* s; unsigned short* d; long off;
    if (b < CVT_W0) { s = s0; d = d0; off = (long)b * 2048; }
    else            { s = s1; d = d1; off = (long)(b - CVT_W0) * 2048; }
    const long i = off + (long)threadIdx.x * 8;
    const float4 a = *(const float4*)(s + i);
    const float4 c = *(const float4*)(s + i + 4);
    ushort8 o;
    o[0] = f2bf(a.x); o[1] = f2bf(a.y); o[2] = f2bf(a.z); o[3] = f2bf(a.w);
    o[4] = f2bf(c.x); o[5] = f2bf(c.y); o[6] = f2bf(c.z); o[7] = f2bf(c.w);
    *(ushort8*)(d + i) = o;
}

// ---------------------------------------------------------------------------
// [QKV] r9 sp kernel + FUSED f32-A conversion (removes the 17-us hidden cvt):
// out[M][N] = cvt_bf16(Af[M][K]) @ B[N][K]^T + bias.
// 256x256, BK=64, 512 threads (8 waves 2Mx4N). A staged as f32
// global_load_dwordx4 -> regs -> f2bf -> ds_write_b128 (T14 issue-early /
// write-late: issue after the barrier, write between quads 1 and 2 into
// region ~cur). B staged via global_load_lds as before.
// Race-freedom: all writes to region ~cur (B gloads AND A ds_writes) are
// one-barrier-separated from other waves' last reads of ~cur, whose
// retirement before barrier-arrival is forced by their own MFMA lgkmcnt
// (r7-r11 validated). Top-of-loop s_waitcnt vmcnt(0) lgkmcnt(0) + barrier
// publishes region cur (B drained, A ds_writes retired).
// T1 XCD swizzle; T2 both-sides 3-bit XOR swizzle (conflict-free, measured
// 0 in r5-r11); T5 setprio.
// ---------------------------------------------------------------------------
template <int OUT_BF16>
__global__ __launch_bounds__(512, 2) void gemm_nt_f32a(
    const float* __restrict__ Af,           // [M][GK] f32
    const unsigned short* __restrict__ B,   // [N][GK] bf16
    const float* __restrict__ bias,         // [N]
    void* __restrict__ outp,                // [M][N] f32 or bf16
    int N, int nbx)                         // nbx = N/256
{
    __shared__ unsigned short sh[65536];    // [2][A 16384 | B 16384], 128 KiB

    const int t = threadIdx.x;
    const int w = t >> 6;
    const int lane = t & 63;
    const int l15 = lane & 15;
    const int g = lane >> 4;

    const int cpx = gridDim.x >> 3;
    const int bid = blockIdx.x;
    const int wg = (bid & 7) * cpx + (bid >> 3);
    const int bm = (wg / nbx) * 256;
    const int bn = (wg % nbx) * 256;

    const int wr = (w >> 2) * 128;
    const int wc = (w & 3) * 64;

    // staging map: thread t covers row tr = t>>3 (within each 64-row block),
    // 8-elem slot t&7; pre-swizzled source col = slot*8 ^ ((tr&7)<<3).
    const int tr = t >> 3;
    const int colsw = ((t & 7) * 8) ^ (((t >> 3) & 7) << 3);
    const float* gAf[4];
    const unsigned short* gB[4];
#pragma unroll
    for (int j = 0; j < 4; ++j) {
        gAf[j] = Af + (size_t)(bm + j * 64 + tr) * GK + colsw;
        gB[j]  = B  + (size_t)(bn + j * 64 + tr) * GK + colsw;
    }
    const int wub = (t & ~63) * 8;

    const int sw = (l15 & 7) << 3;
    const int fk0 = (g * 8) ^ sw;
    const int fk1 = (32 + g * 8) ^ sw;
    int arow[8], brow[4];
#pragma unroll
    for (int mi = 0; mi < 8; ++mi) arow[mi] = (wr + mi * 16 + l15) * 64;
#pragma unroll
    for (int ni = 0; ni < 4; ++ni) brow[ni] = 16384 + (wc + ni * 16 + l15) * 64;

    f32x4 acc[8][4];
#pragma unroll
    for (int mi = 0; mi < 8; ++mi)
#pragma unroll
        for (int ni = 0; ni < 4; ++ni)
            acc[mi][ni] = (f32x4){0.f, 0.f, 0.f, 0.f};

    // B staging (global_load_lds, as r9)
    auto stageB = [&](int tile) {
        if (tile >= NT) return;
        unsigned short* rg = sh + (tile & 1) * 32768 + wub;
        const int ka = tile * 64;
        GLD16(gB[0] + ka, rg + 16384);
        GLD16(gB[1] + ka, rg + 20480);
        GLD16(gB[2] + ka, rg + 24576);
        GLD16(gB[3] + ka, rg + 28672);
    };

    // A f32 issue (regs) and write (cvt + ds_write_b128 into tile&1 region)
    float4 ar[4][2];
    auto issueA = [&](int tile) {
        if (tile >= NT) return;
        const int ka = tile * 64;
#pragma unroll
        for (int j = 0; j < 4; ++j) {
            ar[j][0] = *(const float4*)(gAf[j] + ka);
            ar[j][1] = *(const float4*)(gAf[j] + ka + 4);
        }
    };
    auto writeA = [&](int tile) {
        if (tile >= NT) return;
        unsigned short* rg = sh + (tile & 1) * 32768;
#pragma unroll
        for (int j = 0; j < 4; ++j) {
            ushort8 o;
            o[0] = f2bf(ar[j][0].x); o[1] = f2bf(ar[j][0].y);
            o[2] = f2bf(ar[j][0].z); o[3] = f2bf(ar[j][0].w);
            o[4] = f2bf(ar[j][1].x); o[5] = f2bf(ar[j][1].y);
            o[6] = f2bf(ar[j][1].z); o[7] = f2bf(ar[j][1].w);
            *(ushort8*)(rg + j * 4096 + t * 8) = o;
        }
    };

    bf16x8 afA[4], afB[4], bfrA[4], bfrB[4];

#define MFMA_QUAD(H, AF, BF)                                                  \
    __builtin_amdgcn_s_setprio(1);                                            \
    _Pragma("unroll") for (int mi = 0; mi < 4; ++mi)                          \
    _Pragma("unroll") for (int ni = 0; ni < 4; ++ni)                          \
        acc[(H) * 4 + mi][ni] = __builtin_amdgcn_mfma_f32_16x16x32_bf16(      \
            (AF)[mi], (BF)[ni], acc[(H) * 4 + mi][ni], 0, 0, 0);              \
    __builtin_amdgcn_s_setprio(0);

    // prologue: tile 0 (B via gload; A via reg-cvt)
    stageB(0);
    issueA(0);
    writeA(0);      // compiler inserts vmcnt for ar reads (drains B(0) too)

    for (int kt = 0; kt < NT; ++kt) {
        const unsigned short* base = sh + (kt & 1) * 32768;

        asm volatile("s_waitcnt vmcnt(0) lgkmcnt(0)" ::: "memory");
        SBAR();                               // region kt&1 visible

        stageB(kt + 1);                       // -> region ~cur
        issueA(kt + 1);                       // f32 loads -> regs

#pragma unroll
        for (int ni = 0; ni < 4; ++ni) bfrA[ni] = *(const bf16x8*)(base + brow[ni] + fk0);
#pragma unroll
        for (int mi = 0; mi < 4; ++mi) afA[mi] = *(const bf16x8*)(base + arow[mi] + fk0);
#pragma unroll
        for (int mi = 0; mi < 4; ++mi) afB[mi] = *(const bf16x8*)(base + arow[4 + mi] + fk0);
        MFMA_QUAD(0, afA, bfrA);
#pragma unroll
        for (int ni = 0; ni < 4; ++ni) bfrB[ni] = *(const bf16x8*)(base + brow[ni] + fk1);
#pragma unroll
        for (int mi = 0; mi < 4; ++mi) afA[mi] = *(const bf16x8*)(base + arow[mi] + fk1);
        MFMA_QUAD(1, afB, bfrA);

        writeA(kt + 1);                       // cvt + ds_write -> region ~cur

#pragma unroll
        for (int mi = 0; mi < 4; ++mi) afB[mi] = *(const bf16x8*)(base + arow[4 + mi] + fk1);
        MFMA_QUAD(0, afA, bfrB);
        MFMA_QUAD(1, afB, bfrB);
    }
#undef MFMA_QUAD

    const int orow = bm + wr + g * 4;
    const int ocol = bn + wc + l15;
    float bv[4];
#pragma unroll
    for (int ni = 0; ni < 4; ++ni) bv[ni] = bias[ocol + ni * 16];
#pragma unroll
    for (int mi = 0; mi < 8; ++mi)
#pragma unroll
        for (int ni = 0; ni < 4; ++ni)
#pragma unroll
            for (int r = 0; r < 4; ++r) {
                const int row = orow + mi * 16 + r;
                const int col = ocol + ni * 16;
                const float v = acc[mi][ni][r] + bv[ni];
                if (OUT_BF16)
                    ((unsigned short*)outp)[(size_t)row * N + col] = f2bf(v);
                else
                    ((float*)outp)[(size_t)row * N + col] = v;
            }
}

// ---------------------------------------------------------------------------
// [PROJ] r12's tail-exact 128x160 kernel (kept: proj improved r11->r12).
// ---------------------------------------------------------------------------
template <int BN, int OUT_BF16>
__global__ __launch_bounds__(256, 2) void gemm_nt_bf16_g(
    const unsigned short* __restrict__ A,
    const unsigned short* __restrict__ B,
    const float* __restrict__ bias,
    void* __restrict__ outp,
    int N, int nbx)                         // nbx = N/BN
{
    constexpr int NF   = BN / 32;
    constexpr int BBLK = BN / 32;
    constexpr int REG  = (128 + BN) * 64;

    __shared__ unsigned short sh[2 * REG];

    const int t = threadIdx.x;
    const int w = t >> 6;
    const int lane = t & 63;
    const int l15 = lane & 15;
    const int g = lane >> 4;

    const int cpx = gridDim.x >> 3;
    const int bid = blockIdx.x;
    const int wg = (bid & 7) * cpx + (bid >> 3);
    const int bm = (wg / nbx) * 128;
    const int bn = (wg % nbx) * BN;

    const int wr = (w >> 1) * 64;
    const int wc = (w & 1) * (BN / 2);

    const int tr = t >> 3;
    const int colsw = ((t & 7) * 8) ^ (((t >> 3) & 7) << 3);
    const unsigned short* gA[4];
    const unsigned short* gB[BBLK];
#pragma unroll
    for (int j = 0; j < 4; ++j)
        gA[j] = A + (size_t)(bm + j * 32 + tr) * GK + colsw;
#pragma unroll
    for (int j = 0; j < BBLK; ++j)
        gB[j] = B + (size_t)(bn + j * 32 + tr) * GK + colsw;
    const int wub = (t & ~63) * 8;

    const int sw = (l15 & 7) << 3;
    const int fk0 = (g * 8) ^ sw;
    const int fk1 = (32 + g * 8) ^ sw;
    int arow[4], brow[NF];
#pragma unroll
    for (int mi = 0; mi < 4; ++mi) arow[mi] = (wr + mi * 16 + l15) * 64;
#pragma unroll
    for (int ni = 0; ni < NF; ++ni) brow[ni] = 8192 + (wc + ni * 16 + l15) * 64;

    f32x4 acc[4][NF];
#pragma unroll
    for (int mi = 0; mi < 4; ++mi)
#pragma unroll
        for (int ni = 0; ni < NF; ++ni)
            acc[mi][ni] = (f32x4){0.f, 0.f, 0.f, 0.f};

    auto stageTile = [&](int tile) {
        if (tile >= NT) return;
        unsigned short* rg = sh + (tile & 1) * REG + wub;
        const int ka = tile * 64;
#pragma unroll
        for (int j = 0; j < 4; ++j)
            GLD16(gA[j] + ka, rg + j * 2048);
#pragma unroll
        for (int j = 0; j < BBLK; ++j)
            GLD16(gB[j] + ka, rg + 8192 + j * 2048);
    };

    bf16x8 af0[4], af1[4], bf0[NF], bf1[NF];

#define MFMA_PASS(AF, BF)                                                     \
    __builtin_amdgcn_s_setprio(1);                                            \
    _Pragma("unroll") for (int mi = 0; mi < 4; ++mi)                          \
    _Pragma("unroll") for (int ni = 0; ni < NF; ++ni)                         \
        acc[mi][ni] = __builtin_amdgcn_mfma_f32_16x16x32_bf16(                \
            (AF)[mi], (BF)[ni], acc[mi][ni], 0, 0, 0);                        \
    __builtin_amdgcn_s_setprio(0);

    stageTile(0);

    for (int kt = 0; kt < NT; ++kt) {
        const unsigned short* base = sh + (kt & 1) * REG;

        asm volatile("s_waitcnt vmcnt(0)" ::: "memory");
        SBAR();
        stageTile(kt + 1);

#pragma unroll
        for (int ni = 0; ni < NF; ++ni) bf0[ni] = *(const bf16x8*)(base + brow[ni] + fk0);
#pragma unroll
        for (int mi = 0; mi < 4; ++mi) af0[mi] = *(const bf16x8*)(base + arow[mi] + fk0);
#pragma unroll
        for (int ni = 0; ni < NF; ++ni) bf1[ni] = *(const bf16x8*)(base + brow[ni] + fk1);
#pragma unroll
        for (int mi = 0; mi < 4; ++mi) af1[mi] = *(const bf16x8*)(base + arow[mi] + fk1);
        MFMA_PASS(af0, bf0);
        MFMA_PASS(af1, bf1);
    }
#undef MFMA_PASS

    const int orow = bm + wr + g * 4;
    const int ocol = bn + wc + l15;
    float bv[NF];
#pragma unroll
    for (int ni = 0; ni < NF; ++ni) bv[ni] = bias[ocol + ni * 16];
#pragma unroll
    for (int mi = 0; mi < 4; ++mi)
#pragma unroll
        for (int ni = 0; ni < NF; ++ni)
#pragma unroll
            for (int r = 0; r < 4; ++r) {
                const int row = orow + mi * 16 + r;
                const int col = ocol + ni * 16;
                const float v = acc[mi][ni][r] + bv[ni];
                if (OUT_BF16)
                    ((unsigned short*)outp)[(size_t)row * N + col] = f2bf(v);
                else
                    ((float*)outp)[(size_t)row * N + col] = v;
            }
}

// ---------------------------------------------------------------------------
// MFMA windowed attention (unchanged; ~55 us)
// ---------------------------------------------------------------------------
__global__ __launch_bounds__(256) void win_attn_mfma(
    const unsigned short* __restrict__ qkv,  // [S][3840] bf16
    const float* __restrict__ cosb,          // [S][80]
    const float* __restrict__ sinb,          // [S][80]
    const float* __restrict__ mask,          // [NWIN][64][64]
    unsigned short* __restrict__ attn_out)   // [S][1280] bf16
{
    const int h = blockIdx.x;
    const int win = blockIdx.y;
    const int t = threadIdx.x;
    const int w = t >> 6;
    const int lane = t & 63;
    const int l15 = lane & 15;
    const int g = lane >> 4;

    __shared__ unsigned short Qs[64 * 104];
    __shared__ unsigned short Ks[64 * 104];
    __shared__ unsigned short Vt[80 * 88];
    unsigned short* P = Qs;

    const float scale = 0.11180339887498949f;  // 1/sqrt(80)

    for (int c = t; c < 640; c += 256) {
        const int qk = c / 320;
        const int cc = c % 320;
        const int tok = cc / 5;
        const int dd = (cc % 5) * 8;
        const int tokg = win * 64 + tok;
        const size_t gb = (size_t)tokg * QKV_N + h * HD + qk * DIM;
        const bf16x8 lo = *(const bf16x8*)(qkv + gb + dd);
        const bf16x8 hi = *(const bf16x8*)(qkv + gb + dd + 40);
        float cl[8], sl[8], ch[8], sh[8];
        *(float4*)cl = *(const float4*)(cosb + tokg * HD + dd);
        *(float4*)(cl + 4) = *(const float4*)(cosb + tokg * HD + dd + 4);
        *(float4*)sl = *(const float4*)(sinb + tokg * HD + dd);
        *(float4*)(sl + 4) = *(const float4*)(sinb + tokg * HD + dd + 4);
        *(float4*)ch = *(const float4*)(cosb + tokg * HD + dd + 40);
        *(float4*)(ch + 4) = *(const float4*)(cosb + tokg * HD + dd + 44);
        *(float4*)sh = *(const float4*)(sinb + tokg * HD + dd + 40);
        *(float4*)(sh + 4) = *(const float4*)(sinb + tokg * HD + dd + 44);
        ushort8 olo, ohi;
#pragma unroll
        for (int j = 0; j < 8; ++j) {
            const float x1 = bf2f((unsigned short)lo[j]);
            const float x2 = bf2f((unsigned short)hi[j]);
            float rl = x1 * cl[j] - x2 * sl[j];
            float rh = x2 * ch[j] + x1 * sh[j];
            if (qk == 0) { rl *= scale; rh *= scale; }
            olo[j] = f2bf(rl);
            ohi[j] = f2bf(rh);
        }
        unsigned short* base = (qk ? Ks : Qs) + tok * 104 + dd;
        *(ushort8*)base = olo;
        *(ushort8*)(base + 40) = ohi;
    }
    {
        const int tile = t >> 7, row = (t >> 1) & 63, half = t & 1;
        ushort8 z = (ushort8)0;
        *(ushort8*)((tile ? Ks : Qs) + row * 104 + 80 + half * 8) = z;
    }
    for (int c = t; c < 640; c += 256) {
        const int tok = c / 10;
        const int dd = (c % 10) * 8;
        const bf16x8 vv = *(const bf16x8*)(qkv +
            (size_t)(win * 64 + tok) * QKV_N + h * HD + 2 * DIM + dd);
#pragma unroll
        for (int j = 0; j < 8; ++j)
            Vt[(dd + j) * 88 + tok] = (unsigned short)vv[j];
    }
    __syncthreads();

    f32x4 acc[4];
#pragma unroll
    for (int n = 0; n < 4; ++n) acc[n] = (f32x4){0.f, 0.f, 0.f, 0.f};
#pragma unroll
    for (int ks = 0; ks < 3; ++ks) {
        const int k0 = ks * 32;
        const bf16x8 af = *(const bf16x8*)(Qs + (w * 16 + l15) * 104 + k0 + g * 8);
#pragma unroll
        for (int n = 0; n < 4; ++n) {
            const bf16x8 bfr = *(const bf16x8*)(Ks + (n * 16 + l15) * 104 + k0 + g * 8);
            acc[n] = __builtin_amdgcn_mfma_f32_16x16x32_bf16(af, bfr, acc[n], 0, 0, 0);
        }
    }

    const float* mp = mask + (size_t)win * 4096;
    float pr[4][4];
#pragma unroll
    for (int r = 0; r < 4; ++r) {
        const int row = w * 16 + g * 4 + r;
        float v[4];
#pragma unroll
        for (int n = 0; n < 4; ++n)
            v[n] = acc[n][r] + mp[row * 64 + n * 16 + l15];
        float mx = fmaxf(fmaxf(v[0], v[1]), fmaxf(v[2], v[3]));
        mx = fmaxf(mx, __shfl_xor(mx, 1));
        mx = fmaxf(mx, __shfl_xor(mx, 2));
        mx = fmaxf(mx, __shfl_xor(mx, 4));
        mx = fmaxf(mx, __shfl_xor(mx, 8));
        float sum = 0.f;
#pragma unroll
        for (int n = 0; n < 4; ++n) { v[n] = __expf(v[n] - mx); sum += v[n]; }
        sum += __shfl_xor(sum, 1);
        sum += __shfl_xor(sum, 2);
        sum += __shfl_xor(sum, 4);
        sum += __shfl_xor(sum, 8);
        const float inv = 1.0f / sum;
#pragma unroll
        for (int n = 0; n < 4; ++n) pr[r][n] = v[n] * inv;
    }

    __syncthreads();
#pragma unroll
    for (int r = 0; r < 4; ++r)
#pragma unroll
        for (int n = 0; n < 4; ++n)
            P[(w * 16 + g * 4 + r) * 72 + n * 16 + l15] = f2bf(pr[r][n]);
    __syncthreads();

    f32x4 ao[5];
#pragma unroll
    for (int n = 0; n < 5; ++n) ao[n] = (f32x4){0.f, 0.f, 0.f, 0.f};
#pragma unroll
    for (int ks = 0; ks < 2; ++ks) {
        const int k0 = ks * 32;
        const bf16x8 pa = *(const bf16x8*)(P + (w * 16 + l15) * 72 + k0 + g * 8);
#pragma unroll
        for (int n = 0; n < 5; ++n) {
            const bf16x8 bv = *(const bf16x8*)(Vt + (n * 16 + l15) * 88 + k0 + g * 8);
            ao[n] = __builtin_amdgcn_mfma_f32_16x16x32_bf16(pa, bv, ao[n], 0, 0, 0);
        }
    }

#pragma unroll
    for (int n = 0; n < 5; ++n)
#pragma unroll
        for (int r = 0; r < 4; ++r) {
            const int row = win * 64 + w * 16 + g * 4 + r;
            attn_out[(size_t)row * DIM + h * HD + n * 16 + l15] = f2bf(ao[n][r]);
        }
}

// ---------------------------------------------------------------------------
extern "C" void kernel_launch(void* const* d_in, const int* in_sizes, int n_in,
                              void* d_out, int out_size, void* d_ws, size_t ws_size,
                              hipStream_t stream) {
    const float* hidden = (const float*)d_in[0];
    const float* masks  = (const float*)d_in[1];
    const float* cosb   = (const float*)d_in[2];
    const float* sinb   = (const float*)d_in[3];
    const float* qkv_w  = (const float*)d_in[4];
    const float* qkv_b  = (const float*)d_in[5];
    const float* proj_w = (const float*)d_in[6];
    const float* proj_b = (const float*)d_in[7];
    float* out = (float*)d_out;

    unsigned short* qkv_bf   = (unsigned short*)d_ws;                  // [SEQ][3840]
    unsigned short* attn_bf  = qkv_bf  + (size_t)SEQ * QKV_N;          // [SEQ][1280]
    unsigned short* qkvw_bf  = attn_bf + (size_t)SEQ * DIM;            // [3840][1280]
    unsigned short* projw_bf = qkvw_bf + (size_t)QKV_N * DIM;          // [1280][1280]

    // 0) weights f32->bf16 (hidden conversion fused into QKV GEMM)
    cvt_weights<<<dim3(CVT_W1), 256, 0, stream>>>(qkv_w, qkvw_bf, proj_w, projw_bf);

    // 1) QKV projection with fused A-conversion: 64 x 15 = 960 blocks
    gemm_nt_f32a<1><<<dim3(960), 512, 0, stream>>>(
        hidden, qkvw_bf, qkv_b, (void*)qkv_bf, QKV_N, QKV_N / 256);

    // 2) windowed attention (RoPE fused)
    {
        dim3 grid(NHEAD, NWIN);
        win_attn_mfma<<<grid, 256, 0, stream>>>(qkv_bf, cosb, sinb, masks, attn_bf);
    }

    // 3) output projection: 128x160 tiles -> 1024 blocks @2/CU = 2.00 rounds
    gemm_nt_bf16_g<160, 0><<<dim3(1024), 256, 0, stream>>>(
        attn_bf, projw_bf, proj_b, (void*)out, DIM, DIM / 160);
}

// Round 14
// 303.083 us; speedup vs baseline: 1.2149x; 1.2149x over previous
//
#include <hip/hip_runtime.h>
#include <hip/hip_bf16.h>

#define SEQ 16384
#define DIM 1280
#define NHEAD 16
#define HD 80
#define NWIN 256   // SEQ / 64
#define QKV_N 3840 // 3 * DIM
#define GK 1280    // K of both GEMMs
#define NT 20      // GK / 64

typedef __attribute__((ext_vector_type(8))) short bf16x8;
typedef __attribute__((ext_vector_type(8))) unsigned short ushort8;
typedef __attribute__((ext_vector_type(4))) float f32x4;

__device__ inline unsigned short f2bf(float x) {
    union { __hip_bfloat16 b; unsigned short u; } cv;
    cv.b = __float2bfloat16(x);
    return cv.u;
}
__device__ inline float bf2f(unsigned short u) {
    union { unsigned int i; float f; } cv;
    cv.i = ((unsigned int)u) << 16;
    return cv.f;
}

// async global->LDS, 16B per lane, wave-uniform LDS base + lane*16
#define GLD16(g, l) __builtin_amdgcn_global_load_lds( \
    (const __attribute__((address_space(1))) void*)(g), \
    (__attribute__((address_space(3))) void*)(l), 16, 0, 0)

#define SBAR() asm volatile("s_barrier" ::: "memory")

// ---------------------------------------------------------------------------
// merged f32 -> bf16 convert for all three buffers (one dispatch, r12-best).
// ---------------------------------------------------------------------------
#define CVT_B0 10240   // SEQ*DIM      / 2048
#define CVT_B1 12640   // + QKV_N*DIM  / 2048
#define CVT_B2 13440   // + DIM*DIM    / 2048
__global__ __launch_bounds__(256) void cvt_all(
    const float* __restrict__ s0, unsigned short* __restrict__ d0,
    const float* __restrict__ s1, unsigned short* __restrict__ d1,
    const float* __restrict__ s2, unsigned short* __restrict__ d2)
{
    const int b = blockIdx.x;
    const float* s; unsigned short* d; long off;
    if (b < CVT_B0)      { s = s0; d = d0; off = (long)b * 2048; }
    else if (b < CVT_B1) { s = s1; d = d1; off = (long)(b - CVT_B0) * 2048; }
    else                 { s = s2; d = d2; off = (long)(b - CVT_B1) * 2048; }
    const long i = off + (long)threadIdx.x * 8;
    const float4 a = *(const float4*)(s + i);
    const float4 c = *(const float4*)(s + i + 4);
    ushort8 o;
    o[0] = f2bf(a.x); o[1] = f2bf(a.y); o[2] = f2bf(a.z); o[3] = f2bf(a.w);
    o[4] = f2bf(c.x); o[5] = f2bf(c.y); o[6] = f2bf(c.z); o[7] = f2bf(c.w);
    *(ushort8*)(d + i) = o;
}

// ---------------------------------------------------------------------------
// [QKV] r9/r11 sp kernel — measured best (161 us, MfmaUtil 43.5%, 0 bank
// conflicts, FETCH 182 MB): 256x256, BK=64, 512 threads (8 waves 2Mx4N),
// single-barrier counted loop, sw-pipelined ping-pong frags, both-sides
// 3-bit XOR swizzle, T1 XCD swizzle, T5 setprio.
// ---------------------------------------------------------------------------
template <int OUT_BF16>
__global__ __launch_bounds__(512, 2) void gemm_nt_bf16_sp(
    const unsigned short* __restrict__ A,
    const unsigned short* __restrict__ B,
    const float* __restrict__ bias,
    void* __restrict__ outp,
    int N, int nbx)                         // nbx = N/256
{
    __shared__ unsigned short sh[65536];    // 128 KiB

    const int t = threadIdx.x;
    const int w = t >> 6;
    const int lane = t & 63;
    const int l15 = lane & 15;
    const int g = lane >> 4;

    const int cpx = gridDim.x >> 3;
    const int bid = blockIdx.x;
    const int wg = (bid & 7) * cpx + (bid >> 3);
    const int bm = (wg / nbx) * 256;
    const int bn = (wg % nbx) * 256;

    const int wr = (w >> 2) * 128;
    const int wc = (w & 3) * 64;

    const int colsw = ((t & 7) * 8) ^ (((t >> 3) & 7) << 3);
    const int tr = t >> 3;
    const unsigned short* gA[4];
    const unsigned short* gB[4];
#pragma unroll
    for (int j = 0; j < 4; ++j) {
        gA[j] = A + (size_t)(bm + j * 64 + tr) * GK + colsw;
        gB[j] = B + (size_t)(bn + j * 64 + tr) * GK + colsw;
    }
    const int wub = (t & ~63) * 8;

    const int sw = (l15 & 7) << 3;
    const int fk0 = (g * 8) ^ sw;
    const int fk1 = (32 + g * 8) ^ sw;
    int arow[8], brow[4];
#pragma unroll
    for (int mi = 0; mi < 8; ++mi) arow[mi] = (wr + mi * 16 + l15) * 64;
#pragma unroll
    for (int ni = 0; ni < 4; ++ni) brow[ni] = 16384 + (wc + ni * 16 + l15) * 64;

    f32x4 acc[8][4];
#pragma unroll
    for (int mi = 0; mi < 8; ++mi)
#pragma unroll
        for (int ni = 0; ni < 4; ++ni)
            acc[mi][ni] = (f32x4){0.f, 0.f, 0.f, 0.f};

    auto stageTile = [&](int tile) {
        if (tile >= NT) return;
        unsigned short* rg = sh + (tile & 1) * 32768 + wub;
        const int ka = tile * 64;
        GLD16(gA[0] + ka, rg);
        GLD16(gA[1] + ka, rg + 4096);
        GLD16(gA[2] + ka, rg + 8192);
        GLD16(gA[3] + ka, rg + 12288);
        GLD16(gB[0] + ka, rg + 16384);
        GLD16(gB[1] + ka, rg + 20480);
        GLD16(gB[2] + ka, rg + 24576);
        GLD16(gB[3] + ka, rg + 28672);
    };

    bf16x8 afA[4], afB[4], bfrA[4], bfrB[4];

#define MFMA_QUAD(H, AF, BF)                                                  \
    __builtin_amdgcn_s_setprio(1);                                            \
    _Pragma("unroll") for (int mi = 0; mi < 4; ++mi)                          \
    _Pragma("unroll") for (int ni = 0; ni < 4; ++ni)                          \
        acc[(H) * 4 + mi][ni] = __builtin_amdgcn_mfma_f32_16x16x32_bf16(      \
            (AF)[mi], (BF)[ni], acc[(H) * 4 + mi][ni], 0, 0, 0);              \
    __builtin_amdgcn_s_setprio(0);

    stageTile(0);

    for (int kt = 0; kt < NT; ++kt) {
        const unsigned short* base = sh + (kt & 1) * 32768;

        asm volatile("s_waitcnt vmcnt(0)" ::: "memory");
        SBAR();
        stageTile(kt + 1);

#pragma unroll
        for (int ni = 0; ni < 4; ++ni) bfrA[ni] = *(const bf16x8*)(base + brow[ni] + fk0);
#pragma unroll
        for (int mi = 0; mi < 4; ++mi) afA[mi] = *(const bf16x8*)(base + arow[mi] + fk0);
#pragma unroll
        for (int mi = 0; mi < 4; ++mi) afB[mi] = *(const bf16x8*)(base + arow[4 + mi] + fk0);
        MFMA_QUAD(0, afA, bfrA);
#pragma unroll
        for (int ni = 0; ni < 4; ++ni) bfrB[ni] = *(const bf16x8*)(base + brow[ni] + fk1);
#pragma unroll
        for (int mi = 0; mi < 4; ++mi) afA[mi] = *(const bf16x8*)(base + arow[mi] + fk1);
        MFMA_QUAD(1, afB, bfrA);
#pragma unroll
        for (int mi = 0; mi < 4; ++mi) afB[mi] = *(const bf16x8*)(base + arow[4 + mi] + fk1);
        MFMA_QUAD(0, afA, bfrB);
        MFMA_QUAD(1, afB, bfrB);
    }
#undef MFMA_QUAD

    const int orow = bm + wr + g * 4;
    const int ocol = bn + wc + l15;
    float bv[4];
#pragma unroll
    for (int ni = 0; ni < 4; ++ni) bv[ni] = bias[ocol + ni * 16];
#pragma unroll
    for (int mi = 0; mi < 8; ++mi)
#pragma unroll
        for (int ni = 0; ni < 4; ++ni)
#pragma unroll
            for (int r = 0; r < 4; ++r) {
                const int row = orow + mi * 16 + r;
                const int col = ocol + ni * 16;
                const float v = acc[mi][ni][r] + bv[ni];
                if (OUT_BF16)
                    ((unsigned short*)outp)[(size_t)row * N + col] = f2bf(v);
                else
                    ((float*)outp)[(size_t)row * N + col] = v;
            }
}

// ---------------------------------------------------------------------------
// [PROJ] r12's tail-exact 128x160 kernel — measured best (~56 us).
// ---------------------------------------------------------------------------
template <int BN, int OUT_BF16>
__global__ __launch_bounds__(256, 2) void gemm_nt_bf16_g(
    const unsigned short* __restrict__ A,
    const unsigned short* __restrict__ B,
    const float* __restrict__ bias,
    void* __restrict__ outp,
    int N, int nbx)                         // nbx = N/BN
{
    constexpr int NF   = BN / 32;
    constexpr int BBLK = BN / 32;
    constexpr int REG  = (128 + BN) * 64;

    __shared__ unsigned short sh[2 * REG];

    const int t = threadIdx.x;
    const int w = t >> 6;
    const int lane = t & 63;
    const int l15 = lane & 15;
    const int g = lane >> 4;

    const int cpx = gridDim.x >> 3;
    const int bid = blockIdx.x;
    const int wg = (bid & 7) * cpx + (bid >> 3);
    const int bm = (wg / nbx) * 128;
    const int bn = (wg % nbx) * BN;

    const int wr = (w >> 1) * 64;
    const int wc = (w & 1) * (BN / 2);

    const int tr = t >> 3;
    const int colsw = ((t & 7) * 8) ^ (((t >> 3) & 7) << 3);
    const unsigned short* gA[4];
    const unsigned short* gB[BBLK];
#pragma unroll
    for (int j = 0; j < 4; ++j)
        gA[j] = A + (size_t)(bm + j * 32 + tr) * GK + colsw;
#pragma unroll
    for (int j = 0; j < BBLK; ++j)
        gB[j] = B + (size_t)(bn + j * 32 + tr) * GK + colsw;
    const int wub = (t & ~63) * 8;

    const int sw = (l15 & 7) << 3;
    const int fk0 = (g * 8) ^ sw;
    const int fk1 = (32 + g * 8) ^ sw;
    int arow[4], brow[NF];
#pragma unroll
    for (int mi = 0; mi < 4; ++mi) arow[mi] = (wr + mi * 16 + l15) * 64;
#pragma unroll
    for (int ni = 0; ni < NF; ++ni) brow[ni] = 8192 + (wc + ni * 16 + l15) * 64;

    f32x4 acc[4][NF];
#pragma unroll
    for (int mi = 0; mi < 4; ++mi)
#pragma unroll
        for (int ni = 0; ni < NF; ++ni)
            acc[mi][ni] = (f32x4){0.f, 0.f, 0.f, 0.f};

    auto stageTile = [&](int tile) {
        if (tile >= NT) return;
        unsigned short* rg = sh + (tile & 1) * REG + wub;
        const int ka = tile * 64;
#pragma unroll
        for (int j = 0; j < 4; ++j)
            GLD16(gA[j] + ka, rg + j * 2048);
#pragma unroll
        for (int j = 0; j < BBLK; ++j)
            GLD16(gB[j] + ka, rg + 8192 + j * 2048);
    };

    bf16x8 af0[4], af1[4], bf0[NF], bf1[NF];

#define MFMA_PASS(AF, BF)                                                     \
    __builtin_amdgcn_s_setprio(1);                                            \
    _Pragma("unroll") for (int mi = 0; mi < 4; ++mi)                          \
    _Pragma("unroll") for (int ni = 0; ni < NF; ++ni)                         \
        acc[mi][ni] = __builtin_amdgcn_mfma_f32_16x16x32_bf16(                \
            (AF)[mi], (BF)[ni], acc[mi][ni], 0, 0, 0);                        \
    __builtin_amdgcn_s_setprio(0);

    stageTile(0);

    for (int kt = 0; kt < NT; ++kt) {
        const unsigned short* base = sh + (kt & 1) * REG;

        asm volatile("s_waitcnt vmcnt(0)" ::: "memory");
        SBAR();
        stageTile(kt + 1);

#pragma unroll
        for (int ni = 0; ni < NF; ++ni) bf0[ni] = *(const bf16x8*)(base + brow[ni] + fk0);
#pragma unroll
        for (int mi = 0; mi < 4; ++mi) af0[mi] = *(const bf16x8*)(base + arow[mi] + fk0);
#pragma unroll
        for (int ni = 0; ni < NF; ++ni) bf1[ni] = *(const bf16x8*)(base + brow[ni] + fk1);
#pragma unroll
        for (int mi = 0; mi < 4; ++mi) af1[mi] = *(const bf16x8*)(base + arow[mi] + fk1);
        MFMA_PASS(af0, bf0);
        MFMA_PASS(af1, bf1);
    }
#undef MFMA_PASS

    const int orow = bm + wr + g * 4;
    const int ocol = bn + wc + l15;
    float bv[NF];
#pragma unroll
    for (int ni = 0; ni < NF; ++ni) bv[ni] = bias[ocol + ni * 16];
#pragma unroll
    for (int mi = 0; mi < 4; ++mi)
#pragma unroll
        for (int ni = 0; ni < NF; ++ni)
#pragma unroll
            for (int r = 0; r < 4; ++r) {
                const int row = orow + mi * 16 + r;
                const int col = ocol + ni * 16;
                const float v = acc[mi][ni][r] + bv[ni];
                if (OUT_BF16)
                    ((unsigned short*)outp)[(size_t)row * N + col] = f2bf(v);
                else
                    ((float*)outp)[(size_t)row * N + col] = v;
            }
}

// ---------------------------------------------------------------------------
// MFMA windowed attention (unchanged; ~55 us)
// ---------------------------------------------------------------------------
__global__ __launch_bounds__(256) void win_attn_mfma(
    const unsigned short* __restrict__ qkv,  // [S][3840] bf16
    const float* __restrict__ cosb,          // [S][80]
    const float* __restrict__ sinb,          // [S][80]
    const float* __restrict__ mask,          // [NWIN][64][64]
    unsigned short* __restrict__ attn_out)   // [S][1280] bf16
{
    const int h = blockIdx.x;
    const int win = blockIdx.y;
    const int t = threadIdx.x;
    const int w = t >> 6;
    const int lane = t & 63;
    const int l15 = lane & 15;
    const int g = lane >> 4;

    __shared__ unsigned short Qs[64 * 104];
    __shared__ unsigned short Ks[64 * 104];
    __shared__ unsigned short Vt[80 * 88];
    unsigned short* P = Qs;

    const float scale = 0.11180339887498949f;  // 1/sqrt(80)

    for (int c = t; c < 640; c += 256) {
        const int qk = c / 320;
        const int cc = c % 320;
        const int tok = cc / 5;
        const int dd = (cc % 5) * 8;
        const int tokg = win * 64 + tok;
        const size_t gb = (size_t)tokg * QKV_N + h * HD + qk * DIM;
        const bf16x8 lo = *(const bf16x8*)(qkv + gb + dd);
        const bf16x8 hi = *(const bf16x8*)(qkv + gb + dd + 40);
        float cl[8], sl[8], ch[8], sh[8];
        *(float4*)cl = *(const float4*)(cosb + tokg * HD + dd);
        *(float4*)(cl + 4) = *(const float4*)(cosb + tokg * HD + dd + 4);
        *(float4*)sl = *(const float4*)(sinb + tokg * HD + dd);
        *(float4*)(sl + 4) = *(const float4*)(sinb + tokg * HD + dd + 4);
        *(float4*)ch = *(const float4*)(cosb + tokg * HD + dd + 40);
        *(float4*)(ch + 4) = *(const float4*)(cosb + tokg * HD + dd + 44);
        *(float4*)sh = *(const float4*)(sinb + tokg * HD + dd + 40);
        *(float4*)(sh + 4) = *(const float4*)(sinb + tokg * HD + dd + 44);
        ushort8 olo, ohi;
#pragma unroll
        for (int j = 0; j < 8; ++j) {
            const float x1 = bf2f((unsigned short)lo[j]);
            const float x2 = bf2f((unsigned short)hi[j]);
            float rl = x1 * cl[j] - x2 * sl[j];
            float rh = x2 * ch[j] + x1 * sh[j];
            if (qk == 0) { rl *= scale; rh *= scale; }
            olo[j] = f2bf(rl);
            ohi[j] = f2bf(rh);
        }
        unsigned short* base = (qk ? Ks : Qs) + tok * 104 + dd;
        *(ushort8*)base = olo;
        *(ushort8*)(base + 40) = ohi;
    }
    {
        const int tile = t >> 7, row = (t >> 1) & 63, half = t & 1;
        ushort8 z = (ushort8)0;
        *(ushort8*)((tile ? Ks : Qs) + row * 104 + 80 + half * 8) = z;
    }
    for (int c = t; c < 640; c += 256) {
        const int tok = c / 10;
        const int dd = (c % 10) * 8;
        const bf16x8 vv = *(const bf16x8*)(qkv +
            (size_t)(win * 64 + tok) * QKV_N + h * HD + 2 * DIM + dd);
#pragma unroll
        for (int j = 0; j < 8; ++j)
            Vt[(dd + j) * 88 + tok] = (unsigned short)vv[j];
    }
    __syncthreads();

    f32x4 acc[4];
#pragma unroll
    for (int n = 0; n < 4; ++n) acc[n] = (f32x4){0.f, 0.f, 0.f, 0.f};
#pragma unroll
    for (int ks = 0; ks < 3; ++ks) {
        const int k0 = ks * 32;
        const bf16x8 af = *(const bf16x8*)(Qs + (w * 16 + l15) * 104 + k0 + g * 8);
#pragma unroll
        for (int n = 0; n < 4; ++n) {
            const bf16x8 bfr = *(const bf16x8*)(Ks + (n * 16 + l15) * 104 + k0 + g * 8);
            acc[n] = __builtin_amdgcn_mfma_f32_16x16x32_bf16(af, bfr, acc[n], 0, 0, 0);
        }
    }

    const float* mp = mask + (size_t)win * 4096;
    float pr[4][4];
#pragma unroll
    for (int r = 0; r < 4; ++r) {
        const int row = w * 16 + g * 4 + r;
        float v[4];
#pragma unroll
        for (int n = 0; n < 4; ++n)
            v[n] = acc[n][r] + mp[row * 64 + n * 16 + l15];
        float mx = fmaxf(fmaxf(v[0], v[1]), fmaxf(v[2], v[3]));
        mx = fmaxf(mx, __shfl_xor(mx, 1));
        mx = fmaxf(mx, __shfl_xor(mx, 2));
        mx = fmaxf(mx, __shfl_xor(mx, 4));
        mx = fmaxf(mx, __shfl_xor(mx, 8));
        float sum = 0.f;
#pragma unroll
        for (int n = 0; n < 4; ++n) { v[n] = __expf(v[n] - mx); sum += v[n]; }
        sum += __shfl_xor(sum, 1);
        sum += __shfl_xor(sum, 2);
        sum += __shfl_xor(sum, 4);
        sum += __shfl_xor(sum, 8);
        const float inv = 1.0f / sum;
#pragma unroll
        for (int n = 0; n < 4; ++n) pr[r][n] = v[n] * inv;
    }

    __syncthreads();
#pragma unroll
    for (int r = 0; r < 4; ++r)
#pragma unroll
        for (int n = 0; n < 4; ++n)
            P[(w * 16 + g * 4 + r) * 72 + n * 16 + l15] = f2bf(pr[r][n]);
    __syncthreads();

    f32x4 ao[5];
#pragma unroll
    for (int n = 0; n < 5; ++n) ao[n] = (f32x4){0.f, 0.f, 0.f, 0.f};
#pragma unroll
    for (int ks = 0; ks < 2; ++ks) {
        const int k0 = ks * 32;
        const bf16x8 pa = *(const bf16x8*)(P + (w * 16 + l15) * 72 + k0 + g * 8);
#pragma unroll
        for (int n = 0; n < 5; ++n) {
            const bf16x8 bv = *(const bf16x8*)(Vt + (n * 16 + l15) * 88 + k0 + g * 8);
            ao[n] = __builtin_amdgcn_mfma_f32_16x16x32_bf16(pa, bv, ao[n], 0, 0, 0);
        }
    }

#pragma unroll
    for (int n = 0; n < 5; ++n)
#pragma unroll
        for (int r = 0; r < 4; ++r) {
            const int row = win * 64 + w * 16 + g * 4 + r;
            attn_out[(size_t)row * DIM + h * HD + n * 16 + l15] = f2bf(ao[n][r]);
        }
}

// ---------------------------------------------------------------------------
extern "C" void kernel_launch(void* const* d_in, const int* in_sizes, int n_in,
                              void* d_out, int out_size, void* d_ws, size_t ws_size,
                              hipStream_t stream) {
    const float* hidden = (const float*)d_in[0];
    const float* masks  = (const float*)d_in[1];
    const float* cosb   = (const float*)d_in[2];
    const float* sinb   = (const float*)d_in[3];
    const float* qkv_w  = (const float*)d_in[4];
    const float* qkv_b  = (const float*)d_in[5];
    const float* proj_w = (const float*)d_in[6];
    const float* proj_b = (const float*)d_in[7];
    float* out = (float*)d_out;

    unsigned short* qkv_bf    = (unsigned short*)d_ws;                  // [SEQ][3840]
    unsigned short* attn_bf   = qkv_bf    + (size_t)SEQ * QKV_N;        // [SEQ][1280]
    unsigned short* hidden_bf = attn_bf   + (size_t)SEQ * DIM;          // [SEQ][1280]
    unsigned short* qkvw_bf   = hidden_bf + (size_t)SEQ * DIM;          // [3840][1280]
    unsigned short* projw_bf  = qkvw_bf   + (size_t)QKV_N * DIM;        // [1280][1280]

    // 0) merged f32->bf16 converts (one dispatch)
    cvt_all<<<dim3(CVT_B2), 256, 0, stream>>>(hidden, hidden_bf,
                                              qkv_w, qkvw_bf,
                                              proj_w, projw_bf);

    // 1) QKV projection: 64 x 15 = 960 blocks, 256x256 tiles (sp, best)
    gemm_nt_bf16_sp<1><<<dim3(960), 512, 0, stream>>>(
        hidden_bf, qkvw_bf, qkv_b, (void*)qkv_bf, QKV_N, QKV_N / 256);

    // 2) windowed attention (RoPE fused)
    {
        dim3 grid(NHEAD, NWIN);
        win_attn_mfma<<<grid, 256, 0, stream>>>(qkv_bf, cosb, sinb, masks, attn_bf);
    }

    // 3) output projection: 128x160 tiles -> 1024 blocks @2/CU = 2.00 rounds
    gemm_nt_bf16_g<160, 0><<<dim3(1024), 256, 0, stream>>>(
        attn_bf, projw_bf, proj_b, (void*)out, DIM, DIM / 160);
}